// Round 9
// baseline (29132.404 us; speedup 1.0000x reference)
//
#include <hip/hip_runtime.h>
#include <hip/hip_bf16.h>
#include <stdint.h>

#define TT 1024
#define BB 32
#define DD 1024

typedef __attribute__((ext_vector_type(8))) short short8;
typedef __attribute__((ext_vector_type(4))) unsigned short ushort4v;
typedef __attribute__((ext_vector_type(4))) float floatx4;
typedef __attribute__((ext_vector_type(4))) unsigned uint4v;

static __device__ __forceinline__ unsigned short f2bf(float f){
  unsigned u = __float_as_uint(f);
  u += 0x7fffu + ((u >> 16) & 1u);   // RNE
  return (unsigned short)(u >> 16);
}
static __device__ __forceinline__ float bf2f(unsigned short s){
  return __uint_as_float(((unsigned)s) << 16);
}
static __device__ __forceinline__ float sigm(float x){
  return __fdividef(1.0f, 1.0f + __expf(-x));
}
static __device__ __forceinline__ float fast_tanh(float x){
  float e = __expf(2.0f * x);
  return 1.0f - __fdividef(2.0f, e + 1.0f);
}

// ---------------- workspace layout ----------------
// frag: [t][bh(2)][64KB]: alpha preact fragments (nt 0..63) + wx (nt 64..127), bf16.
// TAGGED H EXCHANGE: h_t (t>=2) lives in the DEAD frag[t-2][bh] block, viewed as
// ull[16][512]: each 8B granule = { lo32 = (h[2c+1]<<16)|h[2c] , hi32 = tagpair },
// tagpair = ((t+1)<<16)|(t+1). Written with ONE relaxed agent 8B atomic store
// (fire-and-forget), read with relaxed agent 8B atomic loads (single-copy atomic:
// matching tag proves the paired h values are current). No fences, no flags, no
// barriers, no placement assumptions. Residue can't fake a tag: pre_gemm residue
// low16s are bf16 activations (tag range 1..1025 = denormal patterns, unreachable);
// prior-replay residue carries identical h values (deterministic), so benign.
#define WS_FRAG_BYTES (134217728ull)                 // 1024*2*64KB
#define WS_WCAT_OFF   (WS_FRAG_BYTES)
#define WS_WCAT_BYTES (4194304ull)
#define WS_H0T_OFF    (WS_WCAT_OFF + WS_WCAT_BYTES)  // tagged h0: 2*16*512 ull = 128KB
#define WS_H1T_OFF    (WS_H0T_OFF + 131072ull)       // tagged h1: 128KB

// ---------------- init: cast weights, tagged h0 (tag=1), zero h1T tags, hout[0]
__global__ void init_kernel(const float* __restrict__ Wa, const float* __restrict__ Wx,
                            const float* __restrict__ h0, float* __restrict__ hout0,
                            unsigned short* __restrict__ Wcat,
                            unsigned long long* __restrict__ h0T,
                            unsigned long long* __restrict__ h1T)
{
  long i = (long)blockIdx.x * 256 + threadIdx.x;
  const long NW = 2048L * 1024L;
  for (long idx = i; idx < NW; idx += (long)gridDim.x * 256L){
    long r = idx >> 10, c = idx & 1023;
    float v = (r < 1024) ? Wa[r*1024 + c] : Wx[(r-1024)*1024 + c];
    Wcat[idx] = f2bf(v);
  }
  const long NG = 32L * 512L;          // granules over [32 rows][512 colpairs]
  for (long idx = i; idx < NG; idx += (long)gridDim.x * 256L){
    long row = idx >> 9, cp = idx & 511;
    float a = h0[row*1024 + 2*cp], b = h0[row*1024 + 2*cp + 1];
    unsigned hpair = ((unsigned)f2bf(b) << 16) | (unsigned)f2bf(a);
    h0T[idx] = ((unsigned long long)0x00010001u << 32) | hpair;   // tag = 1
    h1T[idx] = 0ull;                                              // invalid tags
  }
  const long NH = 32L * 1024L;
  for (long idx = i; idx < NH; idx += (long)gridDim.x * 256L)
    hout0[idx] = h0[idx];              // hout[0] = h0 (fp32)
}

// ---------------- precompute GEMM (unchanged)
__global__ __launch_bounds__(256) void pre_gemm(
    const float* __restrict__ x, const unsigned short* __restrict__ Wcat,
    const float* __restrict__ b_alpha, const float* __restrict__ b_x,
    unsigned short* __restrict__ frag)
{
  __shared__ unsigned short A_lds[128*72];
  __shared__ unsigned short B_lds[128*72];
  const int tid = threadIdx.x;
  const int lane = tid & 63;
  const int w = tid >> 6;
  const int wm = w >> 1, wn = w & 1;
  const long m0 = (long)blockIdx.y * 128;
  const int n0 = blockIdx.x * 128;

  floatx4 acc[4][4];
#pragma unroll
  for (int i=0;i<4;++i)
#pragma unroll
    for (int j=0;j<4;++j) acc[i][j] = (floatx4){0.f,0.f,0.f,0.f};

  for (int kt=0; kt<16; ++kt){
    const int k0 = kt*64;
    __syncthreads();
#pragma unroll
    for (int rep=0; rep<4; ++rep){
      int flat = rep*2048 + tid*8;
      int r = flat >> 6, c = flat & 63;
      const float* src = &x[(m0 + r)*1024 + k0 + c];
      floatx4 f0 = *(const floatx4*)src;
      floatx4 f1 = *(const floatx4*)(src + 4);
      short8 v;
      v[0]=(short)f2bf(f0[0]); v[1]=(short)f2bf(f0[1]); v[2]=(short)f2bf(f0[2]); v[3]=(short)f2bf(f0[3]);
      v[4]=(short)f2bf(f1[0]); v[5]=(short)f2bf(f1[1]); v[6]=(short)f2bf(f1[2]); v[7]=(short)f2bf(f1[3]);
      *(short8*)&A_lds[r*72 + c] = v;
      short8 bv = *(const short8*)&Wcat[(long)(n0 + r)*1024 + k0 + c];
      *(short8*)&B_lds[r*72 + c] = bv;
    }
    __syncthreads();
#pragma unroll
    for (int kb=0; kb<2; ++kb){
      short8 a[4], b[4];
#pragma unroll
      for (int f=0; f<4; ++f)
        a[f] = *(const short8*)&A_lds[(wm*64 + f*16 + (lane&15))*72 + kb*32 + (lane>>4)*8];
#pragma unroll
      for (int f=0; f<4; ++f)
        b[f] = *(const short8*)&B_lds[(wn*64 + f*16 + (lane&15))*72 + kb*32 + (lane>>4)*8];
#pragma unroll
      for (int fm=0; fm<4; ++fm)
#pragma unroll
        for (int fn=0; fn<4; ++fn)
          acc[fm][fn] = __builtin_amdgcn_mfma_f32_16x16x32_bf16(a[fm], b[fn], acc[fm][fn], 0, 0, 0);
    }
  }

#pragma unroll
  for (int fm=0; fm<4; ++fm){
    const long mrow = m0 + wm*64 + fm*16;
    const int t  = (int)(mrow >> 5);
    const int bh = (int)((mrow >> 4) & 1);
#pragma unroll
    for (int fn=0; fn<4; ++fn){
      const int nf  = n0 + wn*64 + fn*16;
      const int nt  = nf >> 4;
      const int col = nf + (lane & 15);
      floatx4 v = acc[fm][fn];
      const float bias = (col < DD) ? b_alpha[col] : b_x[col - DD];
      ushort4v o;
#pragma unroll
      for (int i=0;i<4;++i) o[i] = f2bf(v[i] + bias);
      *(ushort4v*)&frag[((((long)t*2 + bh)*128 + nt)*64 + lane)*4] = o;
    }
  }
}

// ---------------- sequential scan: self-validating tagged exchange
// 32 wgs = 2 groups x 16 slices; after the one-time W_lds fill there are NO
// barriers, NO flags: every wave independently loads tagged h granules and
// retries until all tags match the step id.
__global__ __launch_bounds__(256, 1) void scan_kernel(
    const float* __restrict__ Wh, const float* __restrict__ h0,
    unsigned short* frag,
    unsigned long long* h0T,
    unsigned long long* h1T)
{
  __shared__ unsigned short W_lds[64*1024];  // XOR-swizzled, 128 KB
  const int tid  = threadIdx.x;
  const int lane = tid & 63;
  const int w    = tid >> 6;
  const int bh   = blockIdx.x & 1;
  const int s    = blockIdx.x >> 1;
  const int base_r = s * 64;

  // W_h slice fp32 -> bf16 LDS, 16B-granule XOR swizzle: (r,c) at r*1024 + (c ^ ((r&7)*8))
  for (int it=0; it<64; ++it){
    const int r = it, c = tid*4;
    floatx4 f = *(const floatx4*)&Wh[(long)(base_r + r)*1024 + c];
    ushort4v v;
    v[0]=f2bf(f[0]); v[1]=f2bf(f[1]); v[2]=f2bf(f[2]); v[3]=f2bf(f[3]);
    *(ushort4v*)&W_lds[r*1024 + (c ^ ((r&7)*8))] = v;
  }

  const int colf = base_r + w*16 + (lane & 15);
  const int nt_a = (base_r + w*16) >> 4;
  float hp[4];
#pragma unroll
  for (int i=0;i<4;++i){
    int gb = bh*16 + (lane>>4)*4 + i;
    hp[i] = h0[(long)gb*1024 + colf];
  }
  __syncthreads();   // W_lds ready (the ONLY barrier)

  const int hrow = lane & 15;
  const int g8   = (lane >> 4) * 8;
  const int brow = w*16 + (lane & 15);
  const int boff0 = g8 ^ ((brow & 7) * 8);
  const unsigned short* Wrow = &W_lds[brow * 1024];
  const int ib   = hrow*512 + (g8 >> 1);     // per-lane ull base within [16][512]
  const int ceven = colf & ~1;
  const bool iseven = ((lane & 1) == 0);

  // alpha/wx prefetch: PLAIN cached loads (no virginity constraint anymore)
  long fb = (((long)0*2 + bh)*128 + nt_a)*64 + lane;
  ushort4v al = *(const ushort4v*)&frag[fb*4];
  ushort4v wx = *(const ushort4v*)&frag[(fb + 64*64)*4];

  for (int t=0; t<TT; ++t){
    const unsigned long long* hU =
        (t == 0) ? (h0T + bh*8192) :
        (t == 1) ? (h1T + bh*8192) :
                   (const unsigned long long*)(frag + ((long)(t-2)*2 + bh)*32768);
    const unsigned ttpair = ((unsigned)(t+1) << 16) | (unsigned)(t+1);

    // load ALL granules (32 kbs x 4), self-validate, retry until current
    unsigned long long d[128];
    for (;;){
#pragma unroll
      for (int j=0; j<128; ++j)
        d[j] = __hip_atomic_load(&hU[ib + (j>>2)*16 + (j&3)],
                                 __ATOMIC_RELAXED, __HIP_MEMORY_SCOPE_AGENT);
      unsigned bad = 0;
#pragma unroll
      for (int j=0; j<128; ++j)
        bad |= ((unsigned)(d[j] >> 32)) ^ ttpair;
      if (__all(bad == 0)) break;
      __builtin_amdgcn_s_sleep(1);
    }

    floatx4 ac0 = (floatx4){0.f,0.f,0.f,0.f}, ac1 = ac0, ac2 = ac0, ac3 = ac0;
#pragma unroll
    for (int kb=0; kb<32; ++kb){
      uint4v q = { (unsigned)d[4*kb], (unsigned)d[4*kb+1],
                   (unsigned)d[4*kb+2], (unsigned)d[4*kb+3] };
      short8 afr = __builtin_bit_cast(short8, q);
      short8 bfr = *(const short8*)&Wrow[(kb*32) ^ boff0];
      if ((kb&3)==0) ac0 = __builtin_amdgcn_mfma_f32_16x16x32_bf16(afr, bfr, ac0, 0, 0, 0);
      if ((kb&3)==1) ac1 = __builtin_amdgcn_mfma_f32_16x16x32_bf16(afr, bfr, ac1, 0, 0, 0);
      if ((kb&3)==2) ac2 = __builtin_amdgcn_mfma_f32_16x16x32_bf16(afr, bfr, ac2, 0, 0, 0);
      if ((kb&3)==3) ac3 = __builtin_amdgcn_mfma_f32_16x16x32_bf16(afr, bfr, ac3, 0, 0, 0);
    }
    floatx4 acc = (ac0 + ac1) + (ac2 + ac3);

    // prefetch next alpha/wx (plain, overlaps epilogue+stores)
    ushort4v aln = al, wxn = wx;
    if (t + 1 < TT){
      fb = (((long)(t+1)*2 + bh)*128 + nt_a)*64 + lane;
      aln = *(const ushort4v*)&frag[fb*4];
      wxn = *(const ushort4v*)&frag[(fb + 64*64)*4];
    }

    // epilogue: h_{t+1}, pack pairs via shfl, tagged 8B atomic stores (no drain!)
    unsigned long long* hD =
        (t == 0) ? (h1T + bh*8192)
                 : (unsigned long long*)(frag + ((long)(t-1)*2 + bh)*32768);
    const unsigned ttn = ((unsigned)(t+2) << 16) | (unsigned)(t+2);
#pragma unroll
    for (int i=0;i<4;++i){
      float sv = acc[i] + bf2f(wx[i]);
      float v  = fast_tanh(sv);
      float aa = sigm(bf2f(al[i]));
      float hn = aa*hp[i] + (1.0f - aa)*v;
      hp[i] = hn;
      unsigned us    = (unsigned)f2bf(hn);
      unsigned other = (unsigned)__shfl_xor((int)us, 1, 64);
      if (iseven){
        unsigned hpair = (other << 16) | us;
        unsigned long long pv = ((unsigned long long)ttn << 32) | hpair;
        const int r = (lane>>4)*4 + i;
        __hip_atomic_store(&hD[r*512 + (ceven>>1)], pv,
                           __ATOMIC_RELAXED, __HIP_MEMORY_SCOPE_AGENT);
      }
    }
    al = aln; wx = wxn;
  }
}

// ---------------- expand tagged h -> fp32 out/hout (off critical path)
__global__ __launch_bounds__(256) void out_writer(
    const unsigned short* __restrict__ frag,
    const unsigned long long* __restrict__ h1T,
    float* __restrict__ out, float* __restrict__ hout)
{
  const int t1 = blockIdx.z + 1;          // 1..1024
  const int bh = blockIdx.y;
  const int e  = (blockIdx.x*256 + threadIdx.x)*8;   // h-element index
  const int row = e >> 10, col = e & 1023;
  const unsigned long long* src =
      (t1 == 1) ? (h1T + bh*8192)
                : (const unsigned long long*)(frag + ((long)(t1-2)*2 + bh)*32768);
  const unsigned long long* p = &src[row*512 + (col>>1)];
  float o[8], hh[8];
#pragma unroll
  for (int g=0; g<4; ++g){
    unsigned hpair = (unsigned)p[g];
    float ha = bf2f((unsigned short)(hpair & 0xFFFFu));
    float hb = bf2f((unsigned short)(hpair >> 16));
    float sa = sigm(ha), sb = sigm(hb);
    hh[2*g] = ha;            hh[2*g+1] = hb;
    o[2*g]  = ha*ha*sa;      o[2*g+1]  = hb*hb*sb;
  }
  long ob = ((long)(t1-1)*BB + bh*16 + row)*DD + col;
  long hb = ((long)t1*BB + bh*16 + row)*DD + col;
  *(floatx4*)&out[ob]     = (floatx4){o[0],o[1],o[2],o[3]};
  *(floatx4*)&out[ob+4]   = (floatx4){o[4],o[5],o[6],o[7]};
  *(floatx4*)&hout[hb]    = (floatx4){hh[0],hh[1],hh[2],hh[3]};
  *(floatx4*)&hout[hb+4]  = (floatx4){hh[4],hh[5],hh[6],hh[7]};
}

extern "C" void kernel_launch(void* const* d_in, const int* in_sizes, int n_in,
                              void* d_out, int out_size, void* d_ws, size_t ws_size,
                              hipStream_t stream)
{
  const float* x  = (const float*)d_in[0];
  const float* h0 = (const float*)d_in[1];
  const float* Wa = (const float*)d_in[2];
  const float* ba = (const float*)d_in[3];
  const float* Wh = (const float*)d_in[4];
  const float* Wx = (const float*)d_in[5];
  const float* bx = (const float*)d_in[6];

  float* out  = (float*)d_out;                       // [T,B,D]
  float* hout = out + (long)TT*BB*DD;                // [T+1,B,D]

  uint8_t* ws = (uint8_t*)d_ws;
  unsigned short*     frag = (unsigned short*)(ws);
  unsigned short*     Wcat = (unsigned short*)(ws + WS_WCAT_OFF);
  unsigned long long* h0T  = (unsigned long long*)(ws + WS_H0T_OFF);
  unsigned long long* h1T  = (unsigned long long*)(ws + WS_H1T_OFF);

  init_kernel<<<8192, 256, 0, stream>>>(Wa, Wx, h0, hout, Wcat, h0T, h1T);
  pre_gemm<<<dim3(16, 256), 256, 0, stream>>>(x, Wcat, ba, bx, frag);
  scan_kernel<<<32, 256, 0, stream>>>(Wh, h0, frag, h0T, h1T);
  out_writer<<<dim3(8, 2, 1024), 256, 0, stream>>>(frag, h1T, out, hout);
}

// Round 10
// 3884.741 us; speedup vs baseline: 7.4992x; 7.4992x over previous
//
#include <hip/hip_runtime.h>
#include <hip/hip_bf16.h>
#include <stdint.h>

#define TT 1024
#define BB 32
#define DD 1024

typedef __attribute__((ext_vector_type(8))) short short8;
typedef __attribute__((ext_vector_type(4))) unsigned short ushort4v;
typedef __attribute__((ext_vector_type(4))) float floatx4;
typedef __attribute__((ext_vector_type(4))) unsigned uint4v;

static __device__ __forceinline__ unsigned short f2bf(float f){
  unsigned u = __float_as_uint(f);
  u += 0x7fffu + ((u >> 16) & 1u);   // RNE
  return (unsigned short)(u >> 16);
}
static __device__ __forceinline__ float bf2f(unsigned short s){
  return __uint_as_float(((unsigned)s) << 16);
}
static __device__ __forceinline__ float sigm(float x){
  return __fdividef(1.0f, 1.0f + __expf(-x));
}
static __device__ __forceinline__ float fast_tanh(float x){
  float e = __expf(2.0f * x);
  return 1.0f - __fdividef(2.0f, e + 1.0f);
}

// ---------------- workspace layout ----------------
// frag: [t][bh(2)][64KB block]: alpha fragments (32KB) + wx fragments (32KB).
// Dead block (t-1,bh) is reused at step t as tagged h exchange ull[16][512]:
// granule = { lo32 = packed bf16 pair, hi32 = ((t+1)<<16)|(t+1) }. Fire-and-
// forget relaxed agent atomic stores; relaxed agent atomic loads; tag match ==
// current. No fences/flags/drains. Tag collisions impossible (see R9 analysis:
// bf16 residue hi16s are never 0x0001..0x0401; poison 0xAAAAAAAA invalid;
// replay residue is deterministic-identical hence benign).
#define WS_FRAG_BYTES (134217728ull)
#define WS_WCAT_OFF   (WS_FRAG_BYTES)
#define WS_WCAT_BYTES (4194304ull)
#define WS_H0T_OFF    (WS_WCAT_OFF + WS_WCAT_BYTES)
#define WS_H1T_OFF    (WS_H0T_OFF + 131072ull)

__global__ void init_kernel(const float* __restrict__ Wa, const float* __restrict__ Wx,
                            const float* __restrict__ h0, float* __restrict__ hout0,
                            unsigned short* __restrict__ Wcat,
                            unsigned long long* __restrict__ h0T,
                            unsigned long long* __restrict__ h1T)
{
  long i = (long)blockIdx.x * 256 + threadIdx.x;
  const long NW = 2048L * 1024L;
  for (long idx = i; idx < NW; idx += (long)gridDim.x * 256L){
    long r = idx >> 10, c = idx & 1023;
    float v = (r < 1024) ? Wa[r*1024 + c] : Wx[(r-1024)*1024 + c];
    Wcat[idx] = f2bf(v);
  }
  const long NG = 32L * 512L;
  for (long idx = i; idx < NG; idx += (long)gridDim.x * 256L){
    long row = idx >> 9, cp = idx & 511;
    float a = h0[row*1024 + 2*cp], b = h0[row*1024 + 2*cp + 1];
    unsigned hpair = ((unsigned)f2bf(b) << 16) | (unsigned)f2bf(a);
    h0T[idx] = ((unsigned long long)0x00010001u << 32) | hpair;
    h1T[idx] = 0ull;
  }
  const long NH = 32L * 1024L;
  for (long idx = i; idx < NH; idx += (long)gridDim.x * 256L)
    hout0[idx] = h0[idx];
}

__global__ __launch_bounds__(256) void pre_gemm(
    const float* __restrict__ x, const unsigned short* __restrict__ Wcat,
    const float* __restrict__ b_alpha, const float* __restrict__ b_x,
    unsigned short* __restrict__ frag)
{
  __shared__ unsigned short A_lds[128*72];
  __shared__ unsigned short B_lds[128*72];
  const int tid = threadIdx.x;
  const int lane = tid & 63;
  const int w = tid >> 6;
  const int wm = w >> 1, wn = w & 1;
  const long m0 = (long)blockIdx.y * 128;
  const int n0 = blockIdx.x * 128;

  floatx4 acc[4][4];
#pragma unroll
  for (int i=0;i<4;++i)
#pragma unroll
    for (int j=0;j<4;++j) acc[i][j] = (floatx4){0.f,0.f,0.f,0.f};

  for (int kt=0; kt<16; ++kt){
    const int k0 = kt*64;
    __syncthreads();
#pragma unroll
    for (int rep=0; rep<4; ++rep){
      int flat = rep*2048 + tid*8;
      int r = flat >> 6, c = flat & 63;
      const float* src = &x[(m0 + r)*1024 + k0 + c];
      floatx4 f0 = *(const floatx4*)src;
      floatx4 f1 = *(const floatx4*)(src + 4);
      short8 v;
      v[0]=(short)f2bf(f0[0]); v[1]=(short)f2bf(f0[1]); v[2]=(short)f2bf(f0[2]); v[3]=(short)f2bf(f0[3]);
      v[4]=(short)f2bf(f1[0]); v[5]=(short)f2bf(f1[1]); v[6]=(short)f2bf(f1[2]); v[7]=(short)f2bf(f1[3]);
      *(short8*)&A_lds[r*72 + c] = v;
      short8 bv = *(const short8*)&Wcat[(long)(n0 + r)*1024 + k0 + c];
      *(short8*)&B_lds[r*72 + c] = bv;
    }
    __syncthreads();
#pragma unroll
    for (int kb=0; kb<2; ++kb){
      short8 a[4], b[4];
#pragma unroll
      for (int f=0; f<4; ++f)
        a[f] = *(const short8*)&A_lds[(wm*64 + f*16 + (lane&15))*72 + kb*32 + (lane>>4)*8];
#pragma unroll
      for (int f=0; f<4; ++f)
        b[f] = *(const short8*)&B_lds[(wn*64 + f*16 + (lane&15))*72 + kb*32 + (lane>>4)*8];
#pragma unroll
      for (int fm=0; fm<4; ++fm)
#pragma unroll
        for (int fn=0; fn<4; ++fn)
          acc[fm][fn] = __builtin_amdgcn_mfma_f32_16x16x32_bf16(a[fm], b[fn], acc[fm][fn], 0, 0, 0);
    }
  }

#pragma unroll
  for (int fm=0; fm<4; ++fm){
    const long mrow = m0 + wm*64 + fm*16;
    const int t  = (int)(mrow >> 5);
    const int bh = (int)((mrow >> 4) & 1);
#pragma unroll
    for (int fn=0; fn<4; ++fn){
      const int nf  = n0 + wn*64 + fn*16;
      const int nt  = nf >> 4;
      const int col = nf + (lane & 15);
      floatx4 v = acc[fm][fn];
      const float bias = (col < DD) ? b_alpha[col] : b_x[col - DD];
      ushort4v o;
#pragma unroll
      for (int i=0;i<4;++i) o[i] = f2bf(v[i] + bias);
      *(ushort4v*)&frag[((((long)t*2 + bh)*128 + nt)*64 + lane)*4] = o;
    }
  }
}

// ---------------- scan: tagged exchange + wave-sharded LDS staging + W in regs
__global__ __launch_bounds__(256, 1) void scan_kernel(
    const float* __restrict__ Wh, const float* __restrict__ h0,
    unsigned short* frag,
    unsigned long long* h0T,
    unsigned long long* h1T)
{
  __shared__ unsigned h_lds[16*512];     // 32KB, XOR-swizzled granules
  const int tid  = threadIdx.x;
  const int lane = tid & 63;
  const int w    = tid >> 6;
  const int bh   = blockIdx.x & 1;
  const int s    = blockIdx.x >> 1;
  const int base_r = s * 64;

  const int g8   = (lane >> 4) * 8;
  const int brow = w*16 + (lane & 15);

  // W_h slice row -> registers (fp32 load + convert, one-time)
  short8 Breg[32];
  {
    const float* Wr = &Wh[(long)(base_r + brow)*1024 + g8];
#pragma unroll
    for (int kb=0; kb<32; ++kb){
      floatx4 f0 = *(const floatx4*)&Wr[kb*32];
      floatx4 f1 = *(const floatx4*)&Wr[kb*32 + 4];
      short8 v;
      v[0]=(short)f2bf(f0[0]); v[1]=(short)f2bf(f0[1]); v[2]=(short)f2bf(f0[2]); v[3]=(short)f2bf(f0[3]);
      v[4]=(short)f2bf(f1[0]); v[5]=(short)f2bf(f1[1]); v[6]=(short)f2bf(f1[2]); v[7]=(short)f2bf(f1[3]);
      Breg[kb] = v;
    }
  }

  const int colf = base_r + w*16 + (lane & 15);
  const int nt_a = (base_r + w*16) >> 4;
  float hp[4];
#pragma unroll
  for (int i=0;i<4;++i){
    int gb = bh*16 + (lane>>4)*4 + i;
    hp[i] = h0[(long)gb*1024 + colf];
  }

  const int rowq = w*4 + (lane>>4);      // staging: wave w owns rows w*4..w*4+3
  const int cpl  = lane & 15;
  const int row_a = lane & 15;           // MFMA A row
  const int rsw_w = (rowq & 7) << 2;
  const int rsw_r = (row_a & 7) << 2;

  long fb = (((long)0*2 + bh)*128 + nt_a)*64 + lane;
  ushort4v al = *(const ushort4v*)&frag[fb*4];
  ushort4v wx = *(const ushort4v*)&frag[(fb + 64*64)*4];

  const int ceven = colf & ~1;
  const bool iseven = ((lane & 1) == 0);

  for (int t=0; t<TT; ++t){
    const unsigned long long* hU =
        (t == 0) ? (h0T + bh*8192) :
        (t == 1) ? (h1T + bh*8192) :
                   (const unsigned long long*)(frag + ((long)(t-2)*2 + bh)*32768);
    const unsigned tt = ((unsigned)(t+1) << 16) | (unsigned)(t+1);

    unsigned long long d[32];
    for (;;){
#pragma unroll
      for (int j=0; j<32; ++j)
        d[j] = __hip_atomic_load(&hU[rowq*512 + cpl + 16*j],
                                 __ATOMIC_RELAXED, __HIP_MEMORY_SCOPE_AGENT);
      unsigned bad = 0;
#pragma unroll
      for (int j=0; j<32; ++j)
        bad |= ((unsigned)(d[j] >> 32)) ^ tt;
      if (__all(bad == 0)) break;
    }

#pragma unroll
    for (int j=0; j<32; ++j){
      const int cp = cpl + 16*j;
      h_lds[rowq*512 + (((cp & ~3) ^ rsw_w) | (cp & 3))] = (unsigned)d[j];
    }
    __syncthreads();   // h_lds ready

    floatx4 ac0 = (floatx4){0.f,0.f,0.f,0.f}, ac1 = ac0, ac2 = ac0, ac3 = ac0;
#pragma unroll
    for (int kb=0; kb<32; ++kb){
      uint4v q = *(const uint4v*)&h_lds[row_a*512 + ((kb*16 + (g8>>1)) ^ rsw_r)];
      short8 afr = __builtin_bit_cast(short8, q);
      if ((kb&3)==0) ac0 = __builtin_amdgcn_mfma_f32_16x16x32_bf16(afr, Breg[kb], ac0, 0, 0, 0);
      if ((kb&3)==1) ac1 = __builtin_amdgcn_mfma_f32_16x16x32_bf16(afr, Breg[kb], ac1, 0, 0, 0);
      if ((kb&3)==2) ac2 = __builtin_amdgcn_mfma_f32_16x16x32_bf16(afr, Breg[kb], ac2, 0, 0, 0);
      if ((kb&3)==3) ac3 = __builtin_amdgcn_mfma_f32_16x16x32_bf16(afr, Breg[kb], ac3, 0, 0, 0);
    }
    floatx4 acc = (ac0 + ac1) + (ac2 + ac3);
    __syncthreads();   // h_lds consumed

    unsigned long long* hD =
        (t == 0) ? (h1T + bh*8192)
                 : (unsigned long long*)(frag + ((long)(t-1)*2 + bh)*32768);
    const unsigned ttn = ((unsigned)(t+2) << 16) | (unsigned)(t+2);
#pragma unroll
    for (int i=0;i<4;++i){
      float sv = acc[i] + bf2f(wx[i]);
      float v  = fast_tanh(sv);
      float aa = sigm(bf2f(al[i]));
      float hn = aa*hp[i] + (1.0f - aa)*v;
      hp[i] = hn;
      unsigned us    = (unsigned)f2bf(hn);
      unsigned other = (unsigned)__shfl_xor((int)us, 1, 64);
      if (iseven){
        unsigned hpair = (other << 16) | us;
        unsigned long long pv = ((unsigned long long)ttn << 32) | hpair;
        const int r = (lane>>4)*4 + i;
        __hip_atomic_store(&hD[r*512 + (ceven>>1)], pv,
                           __ATOMIC_RELAXED, __HIP_MEMORY_SCOPE_AGENT);
      }
    }

    if (t + 1 < TT){
      fb = (((long)(t+1)*2 + bh)*128 + nt_a)*64 + lane;
      al = *(const ushort4v*)&frag[fb*4];
      wx = *(const ushort4v*)&frag[(fb + 64*64)*4];
    }
  }
}

__global__ __launch_bounds__(256) void out_writer(
    const unsigned short* __restrict__ frag,
    const unsigned long long* __restrict__ h1T,
    float* __restrict__ out, float* __restrict__ hout)
{
  const int t1 = blockIdx.z + 1;
  const int bh = blockIdx.y;
  const int e  = (blockIdx.x*256 + threadIdx.x)*8;
  const int row = e >> 10, col = e & 1023;
  const unsigned long long* src =
      (t1 == 1) ? (h1T + bh*8192)
                : (const unsigned long long*)(frag + ((long)(t1-2)*2 + bh)*32768);
  const unsigned long long* p = &src[row*512 + (col>>1)];
  float o[8], hh[8];
#pragma unroll
  for (int g=0; g<4; ++g){
    unsigned hpair = (unsigned)p[g];
    float ha = bf2f((unsigned short)(hpair & 0xFFFFu));
    float hb = bf2f((unsigned short)(hpair >> 16));
    float sa = sigm(ha), sb = sigm(hb);
    hh[2*g] = ha;            hh[2*g+1] = hb;
    o[2*g]  = ha*ha*sa;      o[2*g+1]  = hb*hb*sb;
  }
  long ob = ((long)(t1-1)*BB + bh*16 + row)*DD + col;
  long hb = ((long)t1*BB + bh*16 + row)*DD + col;
  *(floatx4*)&out[ob]     = (floatx4){o[0],o[1],o[2],o[3]};
  *(floatx4*)&out[ob+4]   = (floatx4){o[4],o[5],o[6],o[7]};
  *(floatx4*)&hout[hb]    = (floatx4){hh[0],hh[1],hh[2],hh[3]};
  *(floatx4*)&hout[hb+4]  = (floatx4){hh[4],hh[5],hh[6],hh[7]};
}

extern "C" void kernel_launch(void* const* d_in, const int* in_sizes, int n_in,
                              void* d_out, int out_size, void* d_ws, size_t ws_size,
                              hipStream_t stream)
{
  const float* x  = (const float*)d_in[0];
  const float* h0 = (const float*)d_in[1];
  const float* Wa = (const float*)d_in[2];
  const float* ba = (const float*)d_in[3];
  const float* Wh = (const float*)d_in[4];
  const float* Wx = (const float*)d_in[5];
  const float* bx = (const float*)d_in[6];

  float* out  = (float*)d_out;
  float* hout = out + (long)TT*BB*DD;

  uint8_t* ws = (uint8_t*)d_ws;
  unsigned short*     frag = (unsigned short*)(ws);
  unsigned short*     Wcat = (unsigned short*)(ws + WS_WCAT_OFF);
  unsigned long long* h0T  = (unsigned long long*)(ws + WS_H0T_OFF);
  unsigned long long* h1T  = (unsigned long long*)(ws + WS_H1T_OFF);

  init_kernel<<<8192, 256, 0, stream>>>(Wa, Wx, h0, hout, Wcat, h0T, h1T);
  pre_gemm<<<dim3(16, 256), 256, 0, stream>>>(x, Wcat, ba, bx, frag);
  scan_kernel<<<32, 256, 0, stream>>>(Wh, h0, frag, h0T, h1T);
  out_writer<<<dim3(8, 2, 1024), 256, 0, stream>>>(frag, h1T, out, hout);
}